// Round 1
// baseline (7040.282 us; speedup 1.0000x reference)
//
#include <hip/hip_runtime.h>

#define HW   2304      // 48*48
#define W48  48
#define NCOL 4608      // B*HW, B=2

// ---------------------------------------------------------------------------
// Implicit-GEMM conv (fp32), TAPS=9 (3x3 SAME) or TAPS=1 (1x1).
// Y[b][co][n] = bias[co] + sum_{ci,tap} W[co][ci][tap] * X[b][ci][shifted n]
// Tile: 64 (co) x 64 (cols over B*HW), BK=16, 256 threads, 4x4 per thread.
// ---------------------------------------------------------------------------
template<int TAPS>
__global__ __launch_bounds__(256) void conv_gemm(
    const float* __restrict__ X, const float* __restrict__ Wt,
    const float* __restrict__ bias, float* __restrict__ Y,
    int Cin, int Cout)
{
    const int t  = threadIdx.x;
    const int tx = t & 15, ty = t >> 4;
    const int n0 = blockIdx.x * 64;
    const int m0 = blockIdx.y * 64;
    const int K  = Cin * TAPS;

    __shared__ float As[16][68];
    __shared__ float Bs[16][68];

    float acc[4][4] = {};

    const int arow = t >> 2, ac4 = (t & 3) * 4;   // A (weights) load
    const int bkk  = t >> 4, bnn = (t & 15) * 4;  // B (patches) load

    // hoist column coordinate decomposition (loop-invariant)
    int pb[4], py[4], px[4];
#pragma unroll
    for (int i = 0; i < 4; i++) {
        int p = n0 + bnn + i;
        pb[i] = p / HW; int rem = p - pb[i] * HW;
        py[i] = rem / W48; px[i] = rem - py[i] * W48;
    }
    const float* wrow = Wt + (size_t)(m0 + arow) * K + ac4;

    for (int k0 = 0; k0 < K; k0 += 16) {
        float4 a = *(const float4*)(wrow + k0);
        As[ac4+0][arow] = a.x; As[ac4+1][arow] = a.y;
        As[ac4+2][arow] = a.z; As[ac4+3][arow] = a.w;

        int kg = k0 + bkk;
        int ci, ky, kx;
        if (TAPS == 9) { ci = kg / 9; int tap = kg - ci * 9; ky = tap / 3 - 1; kx = tap - (tap / 3) * 3 - 1; }
        else           { ci = kg; ky = 0; kx = 0; }
#pragma unroll
        for (int i = 0; i < 4; i++) {
            int yy = py[i] + ky, xx = px[i] + kx;
            float v = 0.f;
            if (TAPS == 1 || ((unsigned)yy < 48u && (unsigned)xx < 48u))
                v = X[((size_t)pb[i] * Cin + ci) * HW + yy * W48 + xx];
            Bs[bkk][bnn + i] = v;
        }
        __syncthreads();
#pragma unroll
        for (int kk = 0; kk < 16; kk++) {
            float4 a4 = *(const float4*)&As[kk][ty * 4];
            float4 b4 = *(const float4*)&Bs[kk][tx * 4];
            float av[4] = {a4.x, a4.y, a4.z, a4.w};
            float bv[4] = {b4.x, b4.y, b4.z, b4.w};
#pragma unroll
            for (int i = 0; i < 4; i++)
#pragma unroll
                for (int j = 0; j < 4; j++)
                    acc[i][j] = fmaf(av[i], bv[j], acc[i][j]);
        }
        __syncthreads();
    }

#pragma unroll
    for (int i = 0; i < 4; i++) {
        int co = m0 + ty * 4 + i;
        if (co >= Cout) continue;
        float bv = bias ? bias[co] : 0.f;
#pragma unroll
        for (int j = 0; j < 4; j++) {
            int p = n0 + tx * 4 + j;
            int b = p / HW, n = p - b * HW;
            Y[((size_t)b * Cout + co) * HW + n] = acc[i][j] + bv;
        }
    }
}

// ---------------------------------------------------------------------------
// Training-mode BN (+ReLU) over (B,H,W) per channel. One block per channel,
// row staged in LDS so global is read once, written once. In-place safe.
// ---------------------------------------------------------------------------
__global__ __launch_bounds__(256) void bn_relu_kernel(
    const float* __restrict__ Xin, float* __restrict__ Yout,
    const float* __restrict__ g, const float* __restrict__ bb, int C)
{
    const int c = blockIdx.x, t = threadIdx.x;
    __shared__ float buf[NCOL];
    __shared__ float redA[256], redB[256];
    float s = 0.f, s2 = 0.f;
    for (int i = t; i < NCOL; i += 256) {
        int b = i / HW, n = i - b * HW;
        float v = Xin[((size_t)b * C + c) * HW + n];
        buf[i] = v; s += v; s2 += v * v;
    }
    redA[t] = s; redB[t] = s2; __syncthreads();
    for (int st = 128; st > 0; st >>= 1) {
        if (t < st) { redA[t] += redA[t + st]; redB[t] += redB[t + st]; }
        __syncthreads();
    }
    float mean = redA[0] * (1.f / NCOL);
    float var  = redB[0] * (1.f / NCOL) - mean * mean;
    float scale = g[c] * rsqrtf(var + 1e-5f);
    float shift = bb[c] - mean * scale;
    for (int i = t; i < NCOL; i += 256) {
        int b = i / HW, n = i - b * HW;
        Yout[((size_t)b * C + c) * HW + n] = fmaxf(buf[i] * scale + shift, 0.f);
    }
}

// ---------------------------------------------------------------------------
// PAM energy: E[n][m] = sum_{c<64} q[c][n] * k[c][m]   (one batch)
// ---------------------------------------------------------------------------
__global__ __launch_bounds__(256) void pam_energy_kernel(
    const float* __restrict__ q, const float* __restrict__ k, float* __restrict__ E)
{
    const int t = threadIdx.x, tx = t & 15, ty = t >> 4;
    const int n0 = blockIdx.x * 64, m0 = blockIdx.y * 64;
    __shared__ float qs[64][68], ks[64][68];
    {
        int c4 = (t & 15) * 4, r0 = (t >> 4) * 4;
#pragma unroll
        for (int i = 0; i < 4; i++) {
            *(float4*)&qs[r0 + i][c4] = *(const float4*)&q[(size_t)(r0 + i) * HW + n0 + c4];
            *(float4*)&ks[r0 + i][c4] = *(const float4*)&k[(size_t)(r0 + i) * HW + m0 + c4];
        }
    }
    __syncthreads();
    float acc[4][4] = {};
#pragma unroll 4
    for (int c = 0; c < 64; c++) {
        float4 a4 = *(const float4*)&qs[c][ty * 4];
        float4 b4 = *(const float4*)&ks[c][tx * 4];
        float av[4] = {a4.x, a4.y, a4.z, a4.w};
        float bv[4] = {b4.x, b4.y, b4.z, b4.w};
#pragma unroll
        for (int i = 0; i < 4; i++)
#pragma unroll
            for (int j = 0; j < 4; j++)
                acc[i][j] = fmaf(av[i], bv[j], acc[i][j]);
    }
#pragma unroll
    for (int i = 0; i < 4; i++)
#pragma unroll
        for (int j = 0; j < 4; j++)
            E[(size_t)(n0 + ty * 4 + i) * HW + m0 + tx * 4 + j] = acc[i][j];
}

// ---------------------------------------------------------------------------
// Row softmax over 2304 cols, in place. One block per row, row staged in LDS.
// ---------------------------------------------------------------------------
__global__ __launch_bounds__(256) void softmax2304(float* __restrict__ E)
{
    const int t = threadIdx.x;
    float* R = E + (size_t)blockIdx.x * HW;
    __shared__ float buf[HW];
    __shared__ float red[256];
    float m = -1e30f;
    for (int i = t; i < HW; i += 256) { float v = R[i]; buf[i] = v; m = fmaxf(m, v); }
    red[t] = m; __syncthreads();
    for (int st = 128; st > 0; st >>= 1) { if (t < st) red[t] = fmaxf(red[t], red[t + st]); __syncthreads(); }
    m = red[0]; __syncthreads();
    float s = 0.f;
    for (int i = t; i < HW; i += 256) { float e = __expf(buf[i] - m); buf[i] = e; s += e; }
    red[t] = s; __syncthreads();
    for (int st = 128; st > 0; st >>= 1) { if (t < st) red[t] += red[t + st]; __syncthreads(); }
    float inv = 1.f / red[0];
    for (int i = t; i < HW; i += 256) R[i] = buf[i] * inv;
}

// ---------------------------------------------------------------------------
// PAM PV: out[c][n] = gamma * sum_m v[c][m]*attn[n][m] + feat[c][n]  (one batch)
// ---------------------------------------------------------------------------
__global__ __launch_bounds__(256) void pam_pv_kernel(
    const float* __restrict__ v, const float* __restrict__ attn,
    const float* __restrict__ feat, const float* __restrict__ gamma,
    float* __restrict__ out)
{
    const int t = threadIdx.x, tx = t & 15, ty = t >> 4;
    const int n0 = blockIdx.x * 64, c0 = blockIdx.y * 64;
    __shared__ float As[16][68], Bs[16][68];
    float acc[4][4] = {};
    const int lrow = t >> 2, lk4 = (t & 3) * 4;
    for (int k0 = 0; k0 < HW; k0 += 16) {
        float4 a = *(const float4*)&v[(size_t)(c0 + lrow) * HW + k0 + lk4];
        As[lk4+0][lrow] = a.x; As[lk4+1][lrow] = a.y; As[lk4+2][lrow] = a.z; As[lk4+3][lrow] = a.w;
        float4 b = *(const float4*)&attn[(size_t)(n0 + lrow) * HW + k0 + lk4];
        Bs[lk4+0][lrow] = b.x; Bs[lk4+1][lrow] = b.y; Bs[lk4+2][lrow] = b.z; Bs[lk4+3][lrow] = b.w;
        __syncthreads();
#pragma unroll
        for (int kk = 0; kk < 16; kk++) {
            float4 a4 = *(const float4*)&As[kk][ty * 4];
            float4 b4 = *(const float4*)&Bs[kk][tx * 4];
            float av[4] = {a4.x, a4.y, a4.z, a4.w};
            float bv[4] = {b4.x, b4.y, b4.z, b4.w};
#pragma unroll
            for (int i = 0; i < 4; i++)
#pragma unroll
                for (int j = 0; j < 4; j++)
                    acc[i][j] = fmaf(av[i], bv[j], acc[i][j]);
        }
        __syncthreads();
    }
    float g = gamma[0];
#pragma unroll
    for (int i = 0; i < 4; i++)
#pragma unroll
        for (int j = 0; j < 4; j++) {
            size_t idx = (size_t)(c0 + ty * 4 + i) * HW + n0 + tx * 4 + j;
            out[idx] = g * acc[i][j] + feat[idx];
        }
}

// ---------------------------------------------------------------------------
// CAM energy: E[c][d] = sum_n xf[c][n]*xf[d][n]  (grid.z = batch)
// ---------------------------------------------------------------------------
__global__ __launch_bounds__(256) void cam_energy_kernel(
    const float* __restrict__ xf, float* __restrict__ E)
{
    const int t = threadIdx.x, tx = t & 15, ty = t >> 4;
    const int d0 = blockIdx.x * 64, c0 = blockIdx.y * 64, b = blockIdx.z;
    const float* Xb = xf + (size_t)b * 512 * HW;
    float* Eb = E + (size_t)b * 512 * 512;
    __shared__ float As[16][68], Bs[16][68];
    float acc[4][4] = {};
    const int lrow = t >> 2, lk4 = (t & 3) * 4;
    for (int k0 = 0; k0 < HW; k0 += 16) {
        float4 a = *(const float4*)&Xb[(size_t)(c0 + lrow) * HW + k0 + lk4];
        As[lk4+0][lrow] = a.x; As[lk4+1][lrow] = a.y; As[lk4+2][lrow] = a.z; As[lk4+3][lrow] = a.w;
        float4 bq = *(const float4*)&Xb[(size_t)(d0 + lrow) * HW + k0 + lk4];
        Bs[lk4+0][lrow] = bq.x; Bs[lk4+1][lrow] = bq.y; Bs[lk4+2][lrow] = bq.z; Bs[lk4+3][lrow] = bq.w;
        __syncthreads();
#pragma unroll
        for (int kk = 0; kk < 16; kk++) {
            float4 a4 = *(const float4*)&As[kk][ty * 4];
            float4 b4 = *(const float4*)&Bs[kk][tx * 4];
            float av[4] = {a4.x, a4.y, a4.z, a4.w};
            float bv[4] = {b4.x, b4.y, b4.z, b4.w};
#pragma unroll
            for (int i = 0; i < 4; i++)
#pragma unroll
                for (int j = 0; j < 4; j++)
                    acc[i][j] = fmaf(av[i], bv[j], acc[i][j]);
        }
        __syncthreads();
    }
#pragma unroll
    for (int i = 0; i < 4; i++)
#pragma unroll
        for (int j = 0; j < 4; j++)
            Eb[(size_t)(c0 + ty * 4 + i) * 512 + d0 + tx * 4 + j] = acc[i][j];
}

// ---------------------------------------------------------------------------
// CAM softmax: attn = softmax(rowmax - E) == exp(minE - E)/sum. In place.
// One block per row (512 cols). grid = 2*512 rows.
// ---------------------------------------------------------------------------
__global__ __launch_bounds__(256) void cam_softmax_kernel(float* __restrict__ E)
{
    const int t = threadIdx.x;
    float* R = E + (size_t)blockIdx.x * 512;
    __shared__ float red[256];
    float v0 = R[t], v1 = R[t + 256];
    red[t] = fminf(v0, v1); __syncthreads();
    for (int st = 128; st > 0; st >>= 1) { if (t < st) red[t] = fminf(red[t], red[t + st]); __syncthreads(); }
    float mn = red[0]; __syncthreads();
    float e0 = __expf(mn - v0), e1 = __expf(mn - v1);
    red[t] = e0 + e1; __syncthreads();
    for (int st = 128; st > 0; st >>= 1) { if (t < st) red[t] += red[t + st]; __syncthreads(); }
    float inv = 1.f / red[0];
    R[t] = e0 * inv; R[t + 256] = e1 * inv;
}

// ---------------------------------------------------------------------------
// CAM out: out[c][n] = gamma * sum_d attn[c][d]*xf[d][n] + xf[c][n]  (grid.z=b)
// ---------------------------------------------------------------------------
__global__ __launch_bounds__(256) void cam_out_kernel(
    const float* __restrict__ attn, const float* __restrict__ xf,
    const float* __restrict__ gamma, float* __restrict__ out)
{
    const int t = threadIdx.x, tx = t & 15, ty = t >> 4;
    const int n0 = blockIdx.x * 64, c0 = blockIdx.y * 64, b = blockIdx.z;
    const float* Ab = attn + (size_t)b * 512 * 512;
    const float* Xb = xf + (size_t)b * 512 * HW;
    float* Ob = out + (size_t)b * 512 * HW;
    __shared__ float As[16][68], Bs[16][68];
    float acc[4][4] = {};
    const int lrow = t >> 2, lk4 = (t & 3) * 4;   // A transpose load
    const int bkk = t >> 4, bn4 = (t & 15) * 4;   // B direct load
    for (int k0 = 0; k0 < 512; k0 += 16) {
        float4 a = *(const float4*)&Ab[(size_t)(c0 + lrow) * 512 + k0 + lk4];
        As[lk4+0][lrow] = a.x; As[lk4+1][lrow] = a.y; As[lk4+2][lrow] = a.z; As[lk4+3][lrow] = a.w;
        *(float4*)&Bs[bkk][bn4] = *(const float4*)&Xb[(size_t)(k0 + bkk) * HW + n0 + bn4];
        __syncthreads();
#pragma unroll
        for (int kk = 0; kk < 16; kk++) {
            float4 a4 = *(const float4*)&As[kk][ty * 4];
            float4 b4 = *(const float4*)&Bs[kk][tx * 4];
            float av[4] = {a4.x, a4.y, a4.z, a4.w};
            float bv[4] = {b4.x, b4.y, b4.z, b4.w};
#pragma unroll
            for (int i = 0; i < 4; i++)
#pragma unroll
                for (int j = 0; j < 4; j++)
                    acc[i][j] = fmaf(av[i], bv[j], acc[i][j]);
        }
        __syncthreads();
    }
    float g = gamma[0];
#pragma unroll
    for (int i = 0; i < 4; i++)
#pragma unroll
        for (int j = 0; j < 4; j++) {
            size_t idx = (size_t)(c0 + ty * 4 + i) * HW + n0 + tx * 4 + j;
            Ob[idx] = g * acc[i][j] + Xb[idx];
        }
}

// ---------------------------------------------------------------------------
// Final 1x1 convs to 19 channels. Weights staged in LDS; X read once.
// X2 non-null => conv8 on (X1 + X2).
// ---------------------------------------------------------------------------
__global__ __launch_bounds__(256) void conv1x1_out19(
    const float* __restrict__ X1, const float* __restrict__ X2,
    const float* __restrict__ Wt, const float* __restrict__ bias,
    float* __restrict__ Y)
{
    __shared__ float ws[19 * 512];
    const int t = threadIdx.x;
    for (int i = t; i < 19 * 512; i += 256) ws[i] = Wt[i];
    __syncthreads();
    const int b = blockIdx.y, n = blockIdx.x * 256 + t;
    float acc[19];
#pragma unroll
    for (int co = 0; co < 19; co++) acc[co] = bias[co];
    const float* p1 = X1 + (size_t)b * 512 * HW + n;
    const float* p2 = X2 ? X2 + (size_t)b * 512 * HW + n : nullptr;
    for (int ci = 0; ci < 512; ci++) {
        float xv = p1[(size_t)ci * HW];
        if (X2) xv += p2[(size_t)ci * HW];
#pragma unroll
        for (int co = 0; co < 19; co++) acc[co] = fmaf(ws[co * 512 + ci], xv, acc[co]);
    }
#pragma unroll
    for (int co = 0; co < 19; co++) Y[((size_t)b * 19 + co) * HW + n] = acc[co];
}

// ---------------------------------------------------------------------------
extern "C" void kernel_launch(void* const* d_in, const int* in_sizes, int n_in,
                              void* d_out, int out_size, void* d_ws, size_t ws_size,
                              hipStream_t stream)
{
    const float* x    = (const float*)d_in[0];
    const float* w5a  = (const float*)d_in[1];
    const float* g5a  = (const float*)d_in[2];
    const float* b5a  = (const float*)d_in[3];
    const float* w5c  = (const float*)d_in[4];
    const float* g5c  = (const float*)d_in[5];
    const float* b5c  = (const float*)d_in[6];
    const float* wq   = (const float*)d_in[7];
    const float* bq   = (const float*)d_in[8];
    const float* wk   = (const float*)d_in[9];
    const float* bk   = (const float*)d_in[10];
    const float* wv   = (const float*)d_in[11];
    const float* bv   = (const float*)d_in[12];
    const float* gpam = (const float*)d_in[13];
    const float* gcam = (const float*)d_in[14];
    const float* w51  = (const float*)d_in[15];
    const float* g51  = (const float*)d_in[16];
    const float* b51  = (const float*)d_in[17];
    const float* w52  = (const float*)d_in[18];
    const float* g52  = (const float*)d_in[19];
    const float* b52  = (const float*)d_in[20];
    const float* w6   = (const float*)d_in[21];
    const float* b6   = (const float*)d_in[22];
    const float* w7   = (const float*)d_in[23];
    const float* b7   = (const float*)d_in[24];
    const float* w8   = (const float*)d_in[25];
    const float* b8   = (const float*)d_in[26];
    float* out = (float*)d_out;

    float* ws = (float*)d_ws;
    size_t off = 0;
    auto alloc = [&](size_t n) { float* p = ws + off; off += n; return p; };
    float* feat1  = alloc((size_t)2 * 512 * HW);   // conv5a -> BN/ReLU (in place)
    float* feat2  = alloc((size_t)2 * 512 * HW);   // conv5c -> BN/ReLU (in place)
    float* qb     = alloc((size_t)2 * 64 * HW);
    float* kb     = alloc((size_t)2 * 64 * HW);
    float* vb     = alloc((size_t)2 * 512 * HW);   // reused as sc_feat after PAM
    float* energy = alloc((size_t)HW * HW);        // per-batch; reused as sa_conv
    float* safeat = alloc((size_t)2 * 512 * HW);
    float* camE   = alloc((size_t)2 * 512 * 512);
    float* saconv = energy;    // dead after PAM
    float* scfeat = vb;        // dead after PAM
    float* scconv = feat1;     // dead after PAM epilogue
    (void)off; (void)ws_size; (void)in_sizes; (void)n_in; (void)out_size;

    dim3 blk(256);

    // conv5a/conv5c + BN + ReLU
    conv_gemm<9><<<dim3(72, 8), blk, 0, stream>>>(x, w5a, nullptr, feat1, 2048, 512);
    bn_relu_kernel<<<512, blk, 0, stream>>>(feat1, feat1, g5a, b5a, 512);
    conv_gemm<9><<<dim3(72, 8), blk, 0, stream>>>(x, w5c, nullptr, feat2, 2048, 512);
    bn_relu_kernel<<<512, blk, 0, stream>>>(feat2, feat2, g5c, b5c, 512);

    // PAM q/k/v (1x1 convs with bias)
    conv_gemm<1><<<dim3(72, 1), blk, 0, stream>>>(feat1, wq, bq, qb, 512, 64);
    conv_gemm<1><<<dim3(72, 1), blk, 0, stream>>>(feat1, wk, bk, kb, 512, 64);
    conv_gemm<1><<<dim3(72, 8), blk, 0, stream>>>(feat1, wv, bv, vb, 512, 512);

    // PAM attention, per batch (energy buffer reused)
    for (int b = 0; b < 2; b++) {
        pam_energy_kernel<<<dim3(36, 36), blk, 0, stream>>>(
            qb + (size_t)b * 64 * HW, kb + (size_t)b * 64 * HW, energy);
        softmax2304<<<HW, blk, 0, stream>>>(energy);
        pam_pv_kernel<<<dim3(36, 8), blk, 0, stream>>>(
            vb + (size_t)b * 512 * HW, energy, feat1 + (size_t)b * 512 * HW,
            gpam, safeat + (size_t)b * 512 * HW);
    }

    // conv51 + BN + ReLU  (sa_conv lives in the dead energy buffer)
    conv_gemm<9><<<dim3(72, 8), blk, 0, stream>>>(safeat, w51, nullptr, saconv, 512, 512);
    bn_relu_kernel<<<512, blk, 0, stream>>>(saconv, saconv, g51, b51, 512);

    // CAM
    cam_energy_kernel<<<dim3(8, 8, 2), blk, 0, stream>>>(feat2, camE);
    cam_softmax_kernel<<<1024, blk, 0, stream>>>(camE);
    cam_out_kernel<<<dim3(36, 8, 2), blk, 0, stream>>>(camE, feat2, gcam, scfeat);

    // conv52 + BN + ReLU  (sc_conv lives in the dead feat1 buffer)
    conv_gemm<9><<<dim3(72, 8), blk, 0, stream>>>(scfeat, w52, nullptr, scconv, 512, 512);
    bn_relu_kernel<<<512, blk, 0, stream>>>(scconv, scconv, g52, b52, 512);

    // Output heads: order is (sasc_output, sa_output, sc_output)
    conv1x1_out19<<<dim3(9, 2), blk, 0, stream>>>(saconv, nullptr, w6, b6, out + 87552);
    conv1x1_out19<<<dim3(9, 2), blk, 0, stream>>>(scconv, nullptr, w7, b7, out + 2 * 87552);
    conv1x1_out19<<<dim3(9, 2), blk, 0, stream>>>(saconv, scconv, w8, b8, out + 0);
}

// Round 3
// 1685.375 us; speedup vs baseline: 4.1773x; 4.1773x over previous
//
#include <hip/hip_runtime.h>

#define HW     2304      // 48*48
#define W48    48
#define NCOL   4608      // B*HW, B=2
#define XPROWS 2512      // padded 50x50 grid rows (2502 used) rounded up

typedef __bf16 bf16x8 __attribute__((ext_vector_type(8)));
typedef float  f32x4  __attribute__((ext_vector_type(4)));
typedef unsigned short u16x8 __attribute__((ext_vector_type(8)));
typedef unsigned short u16x4 __attribute__((ext_vector_type(4)));

__device__ __forceinline__ unsigned short f2b(float f) {
    union { float f; unsigned u; } c; c.f = f;
    return (unsigned short)((c.u + 0x7fffu + ((c.u >> 16) & 1u)) >> 16);
}
__device__ __forceinline__ float b2f(unsigned short h) {
    union { unsigned u; float f; } c; c.u = ((unsigned)h) << 16;
    return c.f;
}

// ===========================================================================
// Unified MFMA GEMM.
//  A: [Ma][K] rows (bf16, or fp32 if AF32), k-contiguous. batch elem-stride sAb.
//  B: EPI_CONV -> Xp channel-last [rows][Cin] bf16, row = n' + off(tap)
//     else     -> row-major [Nb][K] bf16 rows (clamped at Nb)
//  Tile 128x96, BK=32, 256 thr, 4 waves (2x2), 12x mfma 16x16x32 per step.
// ===========================================================================
enum { EPI_CONV = 0, EPI_ROWS = 1, EPI_PVXP = 2 };

template<int TAPS, bool AF32, int EPI>
__global__ __launch_bounds__(256) void mm(
    const void* __restrict__ Ap_, long sAb,
    const unsigned short* __restrict__ Bp, long sBb,
    int K, int cinShift, int Nb,
    float* __restrict__ Yf, long sYb,
    unsigned short* __restrict__ Ybf, long sYbfb,
    const float* __restrict__ bias,
    const float* __restrict__ gptr,
    const float* __restrict__ Rf, long sRb,
    const unsigned short* __restrict__ Rb, long sRbb)
{
    const int t = threadIdx.x;
    const int b = blockIdx.z;
    const int m0 = blockIdx.y * 128;
    const int n0 = blockIdx.x * 96;
    const int lane = t & 63, wid = t >> 6;
    const int wm = wid >> 1, wn = wid & 1;
    const int l15 = lane & 15, l4 = lane >> 4;

    __shared__ unsigned short As[128 * 40];
    __shared__ unsigned short Bs[96 * 40];

    const unsigned short* Ab16 = nullptr; const float* Ab32 = nullptr;
    if (AF32) Ab32 = (const float*)Ap_ + (size_t)b * sAb;
    else      Ab16 = (const unsigned short*)Ap_ + (size_t)b * sAb;
    const unsigned short* Bb = Bp + (size_t)b * sBb;

    const int nk = K >> 5;

    // chunk coords
    const int rowA = t >> 2, subA = t & 3;          // bf16 A: 16B chunks
    const int rowAf = t >> 3, subAf = t & 7;        // f32 A: float4 chunks
    const int rowB = t >> 2, subB = t & 3;

    u16x8 pa0, pa1, pb0, pb1;
    float4 paf[4];

    auto loadA = [&](int s) {
        if (!AF32) {
            const unsigned short* base = Ab16 + (size_t)(m0 + rowA) * K + s * 32 + subA * 8;
            pa0 = *(const u16x8*)base;
            pa1 = *(const u16x8*)(base + (size_t)64 * K);
        } else {
            const float* base = Ab32 + (size_t)(m0 + rowAf) * K + s * 32 + subAf * 4;
#pragma unroll
            for (int i = 0; i < 4; i++) paf[i] = *(const float4*)(base + (size_t)32 * i * K);
        }
    };
    auto loadB = [&](int s) {
        if (EPI == EPI_CONV) {
            const int k0 = s * 32;
            const int tap = (TAPS == 9) ? (k0 >> cinShift) : 0;
            const int ci0 = k0 & ((1 << cinShift) - 1);
            const int off = (TAPS == 9) ? ((tap / 3) * 50 + (tap % 3)) : 51;
            const unsigned short* base = Bb + ((size_t)(n0 + rowB + off) << cinShift) + ci0 + subB * 8;
            pb0 = *(const u16x8*)base;
            if (t < 128) pb1 = *(const u16x8*)(base + ((size_t)64 << cinShift));
        } else {
            int r0 = n0 + rowB; if (r0 >= Nb) r0 = Nb - 1;
            pb0 = *(const u16x8*)(Bb + (size_t)r0 * K + s * 32 + subB * 8);
            if (t < 128) {
                int r1 = n0 + rowB + 64; if (r1 >= Nb) r1 = Nb - 1;
                pb1 = *(const u16x8*)(Bb + (size_t)r1 * K + s * 32 + subB * 8);
            }
        }
    };

    f32x4 zero = {0.f, 0.f, 0.f, 0.f};
    f32x4 acc[4][3];
#pragma unroll
    for (int i = 0; i < 4; i++)
#pragma unroll
        for (int j = 0; j < 3; j++) acc[i][j] = zero;

    loadA(0); loadB(0);

    for (int s = 0; s < nk; ++s) {
        __syncthreads();
        if (!AF32) {
            *(u16x8*)&As[rowA * 40 + subA * 8] = pa0;
            *(u16x8*)&As[(rowA + 64) * 40 + subA * 8] = pa1;
        } else {
#pragma unroll
            for (int i = 0; i < 4; i++) {
                u16x4 h = { f2b(paf[i].x), f2b(paf[i].y), f2b(paf[i].z), f2b(paf[i].w) };
                *(u16x4*)&As[(rowAf + 32 * i) * 40 + subAf * 4] = h;
            }
        }
        *(u16x8*)&Bs[rowB * 40 + subB * 8] = pb0;
        if (t < 128) *(u16x8*)&Bs[(rowB + 64) * 40 + subB * 8] = pb1;
        __syncthreads();
        if (s + 1 < nk) { loadA(s + 1); loadB(s + 1); }

        bf16x8 af[4], bfr[3];
#pragma unroll
        for (int fi = 0; fi < 4; fi++)
            af[fi] = *(const bf16x8*)&As[(wm * 64 + fi * 16 + l15) * 40 + l4 * 8];
#pragma unroll
        for (int fj = 0; fj < 3; fj++)
            bfr[fj] = *(const bf16x8*)&Bs[(wn * 48 + fj * 16 + l15) * 40 + l4 * 8];
#pragma unroll
        for (int fi = 0; fi < 4; fi++)
#pragma unroll
            for (int fj = 0; fj < 3; fj++)
                acc[fi][fj] = __builtin_amdgcn_mfma_f32_16x16x32_bf16(af[fi], bfr[fj], acc[fi][fj], 0, 0, 0);
    }

    const float g = gptr ? gptr[0] : 1.0f;

    if (EPI == EPI_CONV) {
        float* Yfb = Yf ? Yf + (size_t)b * sYb : nullptr;
        unsigned short* Ybfb = Ybf ? Ybf + (size_t)b * sYbfb : nullptr;
        const float* Rfb = Rf ? Rf + (size_t)b * sRb : nullptr;
#pragma unroll
        for (int fi = 0; fi < 4; fi++) {
            const int co = m0 + wm * 64 + fi * 16 + l4 * 4;
#pragma unroll
            for (int fj = 0; fj < 3; fj++) {
                const int np = n0 + wn * 48 + fj * 16 + l15;
                const int y = np / 50, x = np - y * 50;
                if (x >= 48) continue;
                const int nout = y * 48 + x;
#pragma unroll
                for (int r = 0; r < 4; r++) {
                    float o = g * acc[fi][fj][r];
                    if (bias) o += bias[co + r];
                    if (Rfb) o += Rfb[(size_t)(co + r) * HW + nout];
                    if (Yfb) Yfb[(size_t)(co + r) * HW + nout] = o;
                    if (Ybfb) Ybfb[(size_t)(co + r) * HW + nout] = f2b(o);
                }
            }
        }
    } else if (EPI == EPI_ROWS) {
        float* Yfb = Yf + (size_t)b * sYb;
#pragma unroll
        for (int fi = 0; fi < 4; fi++) {
            const int mr = m0 + wm * 64 + fi * 16 + l4 * 4;
#pragma unroll
            for (int fj = 0; fj < 3; fj++) {
                const int col = n0 + wn * 48 + fj * 16 + l15;
                if (col >= Nb) continue;
#pragma unroll
                for (int r = 0; r < 4; r++)
                    Yfb[(size_t)(mr + r) * Nb + col] = acc[fi][fj][r];
            }
        }
    } else { // EPI_PVXP
        unsigned short* Yb = Ybf + (size_t)b * sYbfb;
        const unsigned short* Rbb = Rb + (size_t)b * sRbb;
#pragma unroll
        for (int fi = 0; fi < 4; fi++) {
            const int ms0 = m0 + wm * 64 + fi * 16 + l4 * 4;
#pragma unroll
            for (int fj = 0; fj < 3; fj++) {
                const int col = n0 + wn * 48 + fj * 16 + l15;
                if (col >= Nb) continue;
#pragma unroll
                for (int r = 0; r < 4; r++) {
                    const int ms = ms0 + r;
                    const int yy = ms / 48, xx = ms - yy * 48;
                    const size_t idx = (size_t)((yy + 1) * 50 + xx + 1) * Nb + col;
                    Yb[idx] = f2b(g * acc[fi][fj][r] + b2f(Rbb[idx]));
                }
            }
        }
    }
}

// ===========================================================================
// fp32 [b][C][2304] -> padded channel-last bf16 Xp [b][XPROWS][C]
// (+ optional hi/lo split c-major bf16 [b][C][2304])
// ===========================================================================
template<bool HILO>
__global__ __launch_bounds__(256) void tpad(
    const float* __restrict__ X, unsigned short* __restrict__ Xp,
    unsigned short* __restrict__ hi, unsigned short* __restrict__ lo, int C)
{
    const int t = threadIdx.x;
    const int tj = t & 31, ti = t >> 5;
    const int n0 = blockIdx.x * 32, c0 = blockIdx.y * 32, b = blockIdx.z;
    __shared__ float sm[32][33];
    const float* Xb = X + ((size_t)b * C + c0) * HW + n0;
#pragma unroll
    for (int ii = 0; ii < 4; ii++) {
        const int c = ti + ii * 8;
        const float v = Xb[(size_t)c * HW + tj];
        sm[c][tj] = v;
        if (HILO) {
            const unsigned short h = f2b(v);
            hi[((size_t)b * C + c0 + c) * HW + n0 + tj] = h;
            lo[((size_t)b * C + c0 + c) * HW + n0 + tj] = f2b(v - b2f(h));
        }
    }
    __syncthreads();
    unsigned short* Xpb = Xp + (size_t)b * XPROWS * C;
#pragma unroll
    for (int ii = 0; ii < 4; ii++) {
        const int n = n0 + ti + ii * 8;
        const int y = n / 48, x = n - y * 48;
        Xpb[(size_t)((y + 1) * 50 + x + 1) * C + c0 + tj] = f2b(sm[tj][ti + ii * 8]);
    }
}

// W [Cout][Cin][9] fp32 -> Wp [Cout][tap*Cin+ci] bf16 (tap-major K)
__global__ __launch_bounds__(256) void wconv3(
    const float* __restrict__ Wf, unsigned short* __restrict__ Wb, int Cin)
{
    const int co = blockIdx.x, ci = blockIdx.y * 256 + threadIdx.x;
    const float* src = Wf + ((size_t)co * Cin + ci) * 9;
    unsigned short* dst = Wb + (size_t)co * 9 * Cin + ci;
#pragma unroll
    for (int tap = 0; tap < 9; tap++) dst[(size_t)tap * Cin] = f2b(src[tap]);
}

__global__ __launch_bounds__(256) void cvt_bf16(
    const float* __restrict__ in, unsigned short* __restrict__ o, int n)
{
    const int i = blockIdx.x * 256 + threadIdx.x;
    if (i < n) o[i] = f2b(in[i]);
}

// ===========================================================================
// Training-mode BN (+ReLU), one block per channel (round-1, unchanged)
// ===========================================================================
__global__ __launch_bounds__(256) void bn_relu_kernel(
    const float* __restrict__ Xin, float* __restrict__ Yout,
    const float* __restrict__ g, const float* __restrict__ bb, int C)
{
    const int c = blockIdx.x, t = threadIdx.x;
    __shared__ float buf[NCOL];
    __shared__ float redA[256], redB[256];
    float s = 0.f, s2 = 0.f;
    for (int i = t; i < NCOL; i += 256) {
        int b = i / HW, n = i - b * HW;
        float v = Xin[((size_t)b * C + c) * HW + n];
        buf[i] = v; s += v; s2 += v * v;
    }
    redA[t] = s; redB[t] = s2; __syncthreads();
    for (int st = 128; st > 0; st >>= 1) {
        if (t < st) { redA[t] += redA[t + st]; redB[t] += redB[t + st]; }
        __syncthreads();
    }
    float mean = redA[0] * (1.f / NCOL);
    float var  = redB[0] * (1.f / NCOL) - mean * mean;
    float scale = g[c] * rsqrtf(var + 1e-5f);
    float shift = bb[c] - mean * scale;
    for (int i = t; i < NCOL; i += 256) {
        int b = i / HW, n = i - b * HW;
        Yout[((size_t)b * C + c) * HW + n] = fmaxf(buf[i] * scale + shift, 0.f);
    }
}

// fp32 1x1 conv (q/k heads, M=64) — round-1, unchanged
template<int TAPS>
__global__ __launch_bounds__(256) void conv_gemm(
    const float* __restrict__ X, const float* __restrict__ Wt,
    const float* __restrict__ bias, float* __restrict__ Y,
    int Cin, int Cout)
{
    const int t  = threadIdx.x;
    const int tx = t & 15, ty = t >> 4;
    const int n0 = blockIdx.x * 64;
    const int m0 = blockIdx.y * 64;
    const int K  = Cin * TAPS;
    __shared__ float As[16][68];
    __shared__ float Bs[16][68];
    float acc[4][4] = {};
    const int arow = t >> 2, ac4 = (t & 3) * 4;
    const int bkk  = t >> 4, bnn = (t & 15) * 4;
    int pb[4], pn[4];
#pragma unroll
    for (int i = 0; i < 4; i++) {
        int p = n0 + bnn + i;
        pb[i] = p / HW; pn[i] = p - pb[i] * HW;
    }
    const float* wrow = Wt + (size_t)(m0 + arow) * K + ac4;
    for (int k0 = 0; k0 < K; k0 += 16) {
        float4 a = *(const float4*)(wrow + k0);
        As[ac4+0][arow] = a.x; As[ac4+1][arow] = a.y;
        As[ac4+2][arow] = a.z; As[ac4+3][arow] = a.w;
        int ci = k0 + bkk;
#pragma unroll
        for (int i = 0; i < 4; i++)
            Bs[bkk][bnn + i] = X[((size_t)pb[i] * Cin + ci) * HW + pn[i]];
        __syncthreads();
#pragma unroll
        for (int kk = 0; kk < 16; kk++) {
            float4 a4 = *(const float4*)&As[kk][ty * 4];
            float4 b4 = *(const float4*)&Bs[kk][tx * 4];
            float av[4] = {a4.x, a4.y, a4.z, a4.w};
            float bv[4] = {b4.x, b4.y, b4.z, b4.w};
#pragma unroll
            for (int i = 0; i < 4; i++)
#pragma unroll
                for (int j = 0; j < 4; j++)
                    acc[i][j] = fmaf(av[i], bv[j], acc[i][j]);
        }
        __syncthreads();
    }
#pragma unroll
    for (int i = 0; i < 4; i++) {
        int co = m0 + ty * 4 + i;
        if (co >= Cout) continue;
        float bv = bias ? bias[co] : 0.f;
#pragma unroll
        for (int j = 0; j < 4; j++) {
            int p = n0 + tx * 4 + j;
            int b = p / HW, n = p - b * HW;
            Y[((size_t)b * Cout + co) * HW + n] = acc[i][j] + bv;
        }
    }
}

// PAM energy (fp32, K=64) — round-1, unchanged
__global__ __launch_bounds__(256) void pam_energy_kernel(
    const float* __restrict__ q, const float* __restrict__ k, float* __restrict__ E)
{
    const int t = threadIdx.x, tx = t & 15, ty = t >> 4;
    const int n0 = blockIdx.x * 64, m0 = blockIdx.y * 64;
    __shared__ float qs[64][68], ks[64][68];
    {
        int c4 = (t & 15) * 4, r0 = (t >> 4) * 4;
#pragma unroll
        for (int i = 0; i < 4; i++) {
            *(float4*)&qs[r0 + i][c4] = *(const float4*)&q[(size_t)(r0 + i) * HW + n0 + c4];
            *(float4*)&ks[r0 + i][c4] = *(const float4*)&k[(size_t)(r0 + i) * HW + m0 + c4];
        }
    }
    __syncthreads();
    float acc[4][4] = {};
#pragma unroll 4
    for (int c = 0; c < 64; c++) {
        float4 a4 = *(const float4*)&qs[c][ty * 4];
        float4 b4 = *(const float4*)&ks[c][tx * 4];
        float av[4] = {a4.x, a4.y, a4.z, a4.w};
        float bv[4] = {b4.x, b4.y, b4.z, b4.w};
#pragma unroll
        for (int i = 0; i < 4; i++)
#pragma unroll
            for (int j = 0; j < 4; j++)
                acc[i][j] = fmaf(av[i], bv[j], acc[i][j]);
    }
#pragma unroll
    for (int i = 0; i < 4; i++)
#pragma unroll
        for (int j = 0; j < 4; j++)
            E[(size_t)(n0 + ty * 4 + i) * HW + m0 + tx * 4 + j] = acc[i][j];
}

// Row softmax over 2304, in place (round-1, unchanged)
__global__ __launch_bounds__(256) void softmax2304(float* __restrict__ E)
{
    const int t = threadIdx.x;
    float* R = E + (size_t)blockIdx.x * HW;
    __shared__ float buf[HW];
    __shared__ float red[256];
    float m = -1e30f;
    for (int i = t; i < HW; i += 256) { float v = R[i]; buf[i] = v; m = fmaxf(m, v); }
    red[t] = m; __syncthreads();
    for (int st = 128; st > 0; st >>= 1) { if (t < st) red[t] = fmaxf(red[t], red[t + st]); __syncthreads(); }
    m = red[0]; __syncthreads();
    float s = 0.f;
    for (int i = t; i < HW; i += 256) { float e = __expf(buf[i] - m); buf[i] = e; s += e; }
    red[t] = s; __syncthreads();
    for (int st = 128; st > 0; st >>= 1) { if (t < st) red[t] += red[t + st]; __syncthreads(); }
    float inv = 1.f / red[0];
    for (int i = t; i < HW; i += 256) R[i] = buf[i] * inv;
}

// CAM softmax with hi/lo fixup: E = E1 + E2 + E2^T; attn = exp(min-E)/sum (bf16)
__global__ __launch_bounds__(256) void cam_sm(
    const float* __restrict__ E1, const float* __restrict__ E2,
    unsigned short* __restrict__ attn)
{
    const int c = blockIdx.x, b = blockIdx.y, t = threadIdx.x;
    const float* E1b = E1 + (size_t)b * 512 * 512;
    const float* E2b = E2 + (size_t)b * 512 * 512;
    float v0 = E1b[(size_t)c * 512 + t]       + E2b[(size_t)c * 512 + t]       + E2b[(size_t)t * 512 + c];
    float v1 = E1b[(size_t)c * 512 + t + 256] + E2b[(size_t)c * 512 + t + 256] + E2b[(size_t)(t + 256) * 512 + c];
    __shared__ float red[256];
    red[t] = fminf(v0, v1); __syncthreads();
    for (int st = 128; st; st >>= 1) { if (t < st) red[t] = fminf(red[t], red[t + st]); __syncthreads(); }
    float mn = red[0]; __syncthreads();
    float e0 = __expf(mn - v0), e1 = __expf(mn - v1);
    red[t] = e0 + e1; __syncthreads();
    for (int st = 128; st; st >>= 1) { if (t < st) red[t] += red[t + st]; __syncthreads(); }
    float inv = 1.f / red[0];
    unsigned short* ab = attn + (size_t)b * 512 * 512 + (size_t)c * 512;
    ab[t] = f2b(e0 * inv); ab[t + 256] = f2b(e1 * inv);
}

// Final 1x1 convs to 19 channels (round-1, unchanged)
__global__ __launch_bounds__(256) void conv1x1_out19(
    const float* __restrict__ X1, const float* __restrict__ X2,
    const float* __restrict__ Wt, const float* __restrict__ bias,
    float* __restrict__ Y)
{
    __shared__ float ws[19 * 512];
    const int t = threadIdx.x;
    for (int i = t; i < 19 * 512; i += 256) ws[i] = Wt[i];
    __syncthreads();
    const int b = blockIdx.y, n = blockIdx.x * 256 + t;
    float acc[19];
#pragma unroll
    for (int co = 0; co < 19; co++) acc[co] = bias[co];
    const float* p1 = X1 + (size_t)b * 512 * HW + n;
    const float* p2 = X2 ? X2 + (size_t)b * 512 * HW + n : nullptr;
    for (int ci = 0; ci < 512; ci++) {
        float xv = p1[(size_t)ci * HW];
        if (X2) xv += p2[(size_t)ci * HW];
#pragma unroll
        for (int co = 0; co < 19; co++) acc[co] = fmaf(ws[co * 512 + ci], xv, acc[co]);
    }
#pragma unroll
    for (int co = 0; co < 19; co++) Y[((size_t)b * 19 + co) * HW + n] = acc[co];
}

// ===========================================================================
extern "C" void kernel_launch(void* const* d_in, const int* in_sizes, int n_in,
                              void* d_out, int out_size, void* d_ws, size_t ws_size,
                              hipStream_t stream)
{
    const float* x    = (const float*)d_in[0];
    const float* w5a  = (const float*)d_in[1];
    const float* g5a  = (const float*)d_in[2];
    const float* b5a  = (const float*)d_in[3];
    const float* w5c  = (const float*)d_in[4];
    const float* g5c  = (const float*)d_in[5];
    const float* b5c  = (const float*)d_in[6];
    const float* wq   = (const float*)d_in[7];
    const float* bq   = (const float*)d_in[8];
    const float* wk   = (const float*)d_in[9];
    const float* bk   = (const float*)d_in[10];
    const float* wv   = (const float*)d_in[11];
    const float* bv   = (const float*)d_in[12];
    const float* gpam = (const float*)d_in[13];
    const float* gcam = (const float*)d_in[14];
    const float* w51  = (const float*)d_in[15];
    const float* g51  = (const float*)d_in[16];
    const float* b51  = (const float*)d_in[17];
    const float* w52  = (const float*)d_in[18];
    const float* g52  = (const float*)d_in[19];
    const float* b52  = (const float*)d_in[20];
    const float* w6   = (const float*)d_in[21];
    const float* b6   = (const float*)d_in[22];
    const float* w7   = (const float*)d_in[23];
    const float* b7   = (const float*)d_in[24];
    const float* w8   = (const float*)d_in[25];
    const float* b8   = (const float*)d_in[26];
    float* out = (float*)d_out;

    char* wsb = (char*)d_ws;
    size_t off = 0;
    auto alloc = [&](size_t bytes) { void* p = wsb + off; off += (bytes + 255) & ~(size_t)255; return p; };

    // persistent
    unsigned short* Xp_x  = (unsigned short*)alloc((size_t)2 * XPROWS * 2048 * 2);  // dies after conv5c -> arena2
    float*          feat1 = (float*)alloc((size_t)2 * 512 * HW * 4);                // -> saconv overlay
    float*          feat2 = (float*)alloc((size_t)2 * 512 * HW * 4);                // -> scconv overlay
    unsigned short* Xp_f1 = (unsigned short*)alloc((size_t)2 * XPROWS * 512 * 2);
    unsigned short* Xp_f2 = (unsigned short*)alloc((size_t)2 * XPROWS * 512 * 2);
    unsigned short* hi_cm = (unsigned short*)alloc((size_t)2 * 512 * HW * 2);
    unsigned short* lo_cm = (unsigned short*)alloc((size_t)2 * 512 * HW * 2);
    float*          qb    = (float*)alloc((size_t)2 * 64 * HW * 4);
    float*          kb    = (float*)alloc((size_t)2 * 64 * HW * 4);
    unsigned short* vbf   = (unsigned short*)alloc((size_t)2 * 512 * HW * 2);
    unsigned short* Wpv   = (unsigned short*)alloc((size_t)512 * 512 * 2);
    // arena1: Wp5a+Wp5c, reused after the big convs
    char* arena1 = (char*)alloc((size_t)2 * 512 * 18432 * 2);
    unsigned short* Wp5a  = (unsigned short*)arena1;
    unsigned short* Wp5c  = (unsigned short*)(arena1 + (size_t)512 * 18432 * 2);
    float*          energy= (float*)arena1;                                          // 21.2MB
    unsigned short* Xp51  = (unsigned short*)(arena1 + 22020096);                    // 5.1MB
    unsigned short* Wp51  = (unsigned short*)(arena1 + 22020096 + 5165056);          // 4.7MB
    unsigned short* Wp52  = (unsigned short*)(arena1 + 22020096 + 5165056 + 4718592);
    // arena2: in Xp_x region
    char* arena2 = (char*)Xp_x;
    float*          scfeat = (float*)arena2;                                          // 9.4MB
    unsigned short* Xp52   = (unsigned short*)(arena2 + 9437184);                     // 5.1MB
    float*          E1     = (float*)(arena2 + 9437184 + 5165056);                    // 2MB
    float*          E2     = (float*)(arena2 + 9437184 + 5165056 + 2097152);          // 2MB
    unsigned short* camattn= (unsigned short*)(arena2 + 9437184 + 5165056 + 2 * 2097152);
    float* saconv = feat1;
    float* scconv = feat2;
    (void)in_sizes; (void)n_in; (void)out_size; (void)ws_size;

    dim3 blk(256);
    const long XF1S = (long)XPROWS * 512;

    // --- prep ---
    hipMemsetAsync(Xp_x,  0, (size_t)2 * XPROWS * 2048 * 2, stream);
    hipMemsetAsync(Xp_f1, 0, (size_t)2 * XPROWS * 512 * 2, stream);
    hipMemsetAsync(Xp_f2, 0, (size_t)2 * XPROWS * 512 * 2, stream);
    wconv3<<<dim3(512, 8), blk, 0, stream>>>(w5a, Wp5a, 2048);
    wconv3<<<dim3(512, 8), blk, 0, stream>>>(w5c, Wp5c, 2048);
    cvt_bf16<<<1024, blk, 0, stream>>>(wv, Wpv, 512 * 512);
    tpad<false><<<dim3(72, 64, 2), blk, 0, stream>>>(x, Xp_x, nullptr, nullptr, 2048);

    // --- conv5a / conv5c + BN ---
    mm<9, false, EPI_CONV><<<dim3(25, 4, 2), blk, 0, stream>>>(
        Wp5a, 0, Xp_x, (long)XPROWS * 2048, 18432, 11, 0,
        feat1, (long)512 * HW, nullptr, 0, nullptr, nullptr, nullptr, 0, nullptr, 0);
    bn_relu_kernel<<<512, blk, 0, stream>>>(feat1, feat1, g5a, b5a, 512);
    mm<9, false, EPI_CONV><<<dim3(25, 4, 2), blk, 0, stream>>>(
        Wp5c, 0, Xp_x, (long)XPROWS * 2048, 18432, 11, 0,
        feat2, (long)512 * HW, nullptr, 0, nullptr, nullptr, nullptr, 0, nullptr, 0);
    bn_relu_kernel<<<512, blk, 0, stream>>>(feat2, feat2, g5c, b5c, 512);
    // Xp_x dead -> arena2 usable; Wp5a/5c dead after these convs -> arena1 reuse
    hipMemsetAsync(Xp51, 0, (size_t)2 * XPROWS * 512 * 2, stream);
    hipMemsetAsync(Xp52, 0, (size_t)2 * XPROWS * 512 * 2, stream);

    tpad<false><<<dim3(72, 16, 2), blk, 0, stream>>>(feat1, Xp_f1, nullptr, nullptr, 512);
    tpad<true ><<<dim3(72, 16, 2), blk, 0, stream>>>(feat2, Xp_f2, hi_cm, lo_cm, 512);

    // --- PAM q/k/v ---
    mm<1, false, EPI_CONV><<<dim3(25, 4, 2), blk, 0, stream>>>(
        Wpv, 0, Xp_f1, XF1S, 512, 9, 0,
        nullptr, 0, vbf, (long)512 * HW, bv, nullptr, nullptr, 0, nullptr, 0);
    conv_gemm<1><<<dim3(72, 1), blk, 0, stream>>>(feat1, wq, bq, qb, 512, 64);
    conv_gemm<1><<<dim3(72, 1), blk, 0, stream>>>(feat1, wk, bk, kb, 512, 64);
    wconv3<<<dim3(512, 2), blk, 0, stream>>>(w51, Wp51, 512);
    wconv3<<<dim3(512, 2), blk, 0, stream>>>(w52, Wp52, 512);

    // --- PAM attention per batch; PV writes padded sa_featT directly ---
    for (int b = 0; b < 2; b++) {
        pam_energy_kernel<<<dim3(36, 36), blk, 0, stream>>>(
            qb + (size_t)b * 64 * HW, kb + (size_t)b * 64 * HW, energy);
        softmax2304<<<HW, blk, 0, stream>>>(energy);
        mm<1, true, EPI_PVXP><<<dim3(6, 18, 1), blk, 0, stream>>>(
            energy, 0, vbf + (size_t)b * 512 * HW, 0, HW, 0, 512,
            nullptr, 0, Xp51 + (size_t)b * XPROWS * 512, 0,
            nullptr, gpam, nullptr, 0, Xp_f1 + (size_t)b * XPROWS * 512, 0);
    }

    // --- conv51 + BN (saconv overlays feat1) ---
    mm<9, false, EPI_CONV><<<dim3(25, 4, 2), blk, 0, stream>>>(
        Wp51, 0, Xp51, XF1S, 4608, 9, 0,
        saconv, (long)512 * HW, nullptr, 0, nullptr, nullptr, nullptr, 0, nullptr, 0);
    bn_relu_kernel<<<512, blk, 0, stream>>>(saconv, saconv, g51, b51, 512);

    // --- CAM: split-bf16 Gram, softmax, out ---
    mm<1, false, EPI_ROWS><<<dim3(6, 4, 2), blk, 0, stream>>>(
        hi_cm, (long)512 * HW, hi_cm, (long)512 * HW, HW, 0, 512,
        E1, (long)512 * 512, nullptr, 0, nullptr, nullptr, nullptr, 0, nullptr, 0);
    mm<1, false, EPI_ROWS><<<dim3(6, 4, 2), blk, 0, stream>>>(
        hi_cm, (long)512 * HW, lo_cm, (long)512 * HW, HW, 0, 512,
        E2, (long)512 * 512, nullptr, 0, nullptr, nullptr, nullptr, 0, nullptr, 0);
    cam_sm<<<dim3(512, 2), blk, 0, stream>>>(E1, E2, camattn);
    mm<1, false, EPI_CONV><<<dim3(25, 4, 2), blk, 0, stream>>>(
        camattn, (long)512 * 512, Xp_f2, XF1S, 512, 9, 0,
        scfeat, (long)512 * HW, nullptr, 0, nullptr, gcam, feat2, (long)512 * HW, nullptr, 0);

    // --- conv52 + BN (scconv overlays feat2, dead after cam residual) ---
    tpad<false><<<dim3(72, 16, 2), blk, 0, stream>>>(scfeat, Xp52, nullptr, nullptr, 512);
    mm<9, false, EPI_CONV><<<dim3(25, 4, 2), blk, 0, stream>>>(
        Wp52, 0, Xp52, XF1S, 4608, 9, 0,
        scconv, (long)512 * HW, nullptr, 0, nullptr, nullptr, nullptr, 0, nullptr, 0);
    bn_relu_kernel<<<512, blk, 0, stream>>>(scconv, scconv, g52, b52, 512);

    // --- output heads: (sasc, sa, sc) ---
    conv1x1_out19<<<dim3(9, 2), blk, 0, stream>>>(saconv, nullptr, w6, b6, out + 87552);
    conv1x1_out19<<<dim3(9, 2), blk, 0, stream>>>(scconv, nullptr, w7, b7, out + 2 * 87552);
    conv1x1_out19<<<dim3(9, 2), blk, 0, stream>>>(saconv, scconv, w8, b8, out + 0);
}

// Round 4
// 1163.727 us; speedup vs baseline: 6.0498x; 1.4483x over previous
//
#include <hip/hip_runtime.h>

#define HW     2304      // 48*48
#define W48    48
#define NCOL   4608      // B*HW, B=2
#define XPROWS 2560      // padded 50x50 grid rows + B-load overhang (max row 2533)

typedef __bf16 bf16x8 __attribute__((ext_vector_type(8)));
typedef float  f32x4  __attribute__((ext_vector_type(4)));
typedef unsigned short u16x8 __attribute__((ext_vector_type(8)));
typedef unsigned short u16x4 __attribute__((ext_vector_type(4)));

__device__ __forceinline__ unsigned short f2b(float f) {
    union { float f; unsigned u; } c; c.f = f;
    return (unsigned short)((c.u + 0x7fffu + ((c.u >> 16) & 1u)) >> 16);
}
__device__ __forceinline__ float b2f(unsigned short h) {
    union { unsigned u; float f; } c; c.u = ((unsigned)h) << 16;
    return c.f;
}

// ===========================================================================
// Unified MFMA GEMM. Tile 128(M) x 64(N), BK=32, 256 thr, 4 waves (2x2),
// wave-tile 64x32 -> 8 mfma_16x16x32_bf16 per wave per k-step.
// Prefetch depth 2 (two named register sets). Bijective XCD swizzle (T1).
//  A: [Ma][K] rows (bf16, or fp32 if AF32), k-contiguous. batch elem-stride sAb.
//  B: EPI_CONV -> Xp channel-last [rows][Cin] bf16, row = n' + off(tap)
//     else     -> row-major [Nb][K] bf16 rows (clamped at Nb)
//  Msplit/Yf2: rows >= Msplit of the output go to Yf2 (merged conv5a+5c).
// ===========================================================================
enum { EPI_CONV = 0, EPI_ROWS = 1, EPI_PVXP = 2 };

template<int TAPS, bool AF32, int EPI>
__global__ __launch_bounds__(256) void mm(
    const void* __restrict__ Ap_, long sAb,
    const unsigned short* __restrict__ Bp, long sBb,
    int K, int cinShift, int Nb,
    float* __restrict__ Yf, long sYb, int Msplit, float* __restrict__ Yf2,
    unsigned short* __restrict__ Ybf, long sYbfb,
    const float* __restrict__ bias,
    const float* __restrict__ gptr,
    const float* __restrict__ Rf, long sRb,
    const unsigned short* __restrict__ Rb, long sRbb)
{
    const int t = threadIdx.x;
    // ---- bijective XCD-contiguous swizzle (m204): xcd=bid%8 gets a
    // contiguous chunk of the logical (n-fastest) ordering -> all n-blocks of
    // one (m,b) stream the same A/B through one XCD L2.
    const int gx = gridDim.x, gy = gridDim.y;
    const int bid = blockIdx.x + gx * (blockIdx.y + gy * blockIdx.z);
    const int T = gx * gy * gridDim.z;
    const int q = T >> 3, r = T & 7;
    const int xcd = bid & 7, sl = bid >> 3;
    const int lid = (xcd < r ? xcd * (q + 1) : r * (q + 1) + (xcd - r) * q) + sl;
    const int n0 = (lid % gx) * 64;
    const int tmp = lid / gx;
    const int m0 = (tmp % gy) * 128;
    const int b = tmp / gy;

    const int lane = t & 63, wid = t >> 6;
    const int wm = wid >> 1, wn = wid & 1;
    const int l15 = lane & 15, l4 = lane >> 4;

    __shared__ unsigned short As[128 * 40];
    __shared__ unsigned short Bs[64 * 40];

    const unsigned short* Ab16 = nullptr; const float* Ab32 = nullptr;
    if (AF32) Ab32 = (const float*)Ap_ + (size_t)b * sAb;
    else      Ab16 = (const unsigned short*)Ap_ + (size_t)b * sAb;
    const unsigned short* Bb = Bp + (size_t)b * sBb;

    const int nk = K >> 5;   // all K here are multiples of 64 -> nk even

    const int rowA  = t >> 2, subA  = t & 3;   // bf16 A: 16B chunks, rows 0-63 / 64-127
    const int rowAf = t >> 3, subAf = t & 7;   // f32 A: float4 chunks, 4x 32-row blocks
    const int rowB  = t >> 2, subB  = t & 3;   // B: 64 rows x 4 chunks

    u16x8 a0A, a1A, b0A, a0B, a1B, b0B;
    float4 fA[4], fB[4];

    auto loadA_ = [&](int s, u16x8& r0, u16x8& r1, float4* pf) {
        if (!AF32) {
            const unsigned short* base = Ab16 + (size_t)(m0 + rowA) * K + s * 32 + subA * 8;
            r0 = *(const u16x8*)base;
            r1 = *(const u16x8*)(base + (size_t)64 * K);
        } else {
            const float* base = Ab32 + (size_t)(m0 + rowAf) * K + s * 32 + subAf * 4;
#pragma unroll
            for (int i = 0; i < 4; i++) pf[i] = *(const float4*)(base + (size_t)32 * i * K);
        }
    };
    auto loadB_ = [&](int s, u16x8& r0) {
        if (EPI == EPI_CONV) {
            const int k0 = s * 32;
            const int tap = (TAPS == 9) ? (k0 >> cinShift) : 0;
            const int ci0 = k0 & ((1 << cinShift) - 1);
            const int off = (TAPS == 9) ? ((tap / 3) * 50 + (tap % 3)) : 51;
            r0 = *(const u16x8*)(Bb + ((size_t)(n0 + rowB + off) << cinShift) + ci0 + subB * 8);
        } else {
            int rr = n0 + rowB; if (rr >= Nb) rr = Nb - 1;
            r0 = *(const u16x8*)(Bb + (size_t)rr * K + s * 32 + subB * 8);
        }
    };
    auto store_ = [&](const u16x8& r0, const u16x8& r1, const float4* pf, const u16x8& bb0) {
        if (!AF32) {
            *(u16x8*)&As[rowA * 40 + subA * 8] = r0;
            *(u16x8*)&As[(rowA + 64) * 40 + subA * 8] = r1;
        } else {
#pragma unroll
            for (int i = 0; i < 4; i++) {
                u16x4 h = { f2b(pf[i].x), f2b(pf[i].y), f2b(pf[i].z), f2b(pf[i].w) };
                *(u16x4*)&As[(rowAf + 32 * i) * 40 + subAf * 4] = h;
            }
        }
        *(u16x8*)&Bs[rowB * 40 + subB * 8] = bb0;
    };

    f32x4 zero = {0.f, 0.f, 0.f, 0.f};
    f32x4 acc[4][2];
#pragma unroll
    for (int i = 0; i < 4; i++)
#pragma unroll
        for (int j = 0; j < 2; j++) acc[i][j] = zero;

    auto compute_ = [&]() {
        bf16x8 af[4], bf2[2];
#pragma unroll
        for (int fi = 0; fi < 4; fi++)
            af[fi] = *(const bf16x8*)&As[(wm * 64 + fi * 16 + l15) * 40 + l4 * 8];
#pragma unroll
        for (int fj = 0; fj < 2; fj++)
            bf2[fj] = *(const bf16x8*)&Bs[(wn * 32 + fj * 16 + l15) * 40 + l4 * 8];
#pragma unroll
        for (int fi = 0; fi < 4; fi++)
#pragma unroll
            for (int fj = 0; fj < 2; fj++)
                acc[fi][fj] = __builtin_amdgcn_mfma_f32_16x16x32_bf16(af[fi], bf2[fj], acc[fi][fj], 0, 0, 0);
    };

    loadA_(0, a0A, a1A, fA); loadB_(0, b0A);
    loadA_(1, a0B, a1B, fB); loadB_(1, b0B);

    for (int s = 0; s < nk; s += 2) {
        __syncthreads();
        store_(a0A, a1A, fA, b0A);
        __syncthreads();
        if (s + 2 < nk) { loadA_(s + 2, a0A, a1A, fA); loadB_(s + 2, b0A); }
        compute_();
        __syncthreads();
        store_(a0B, a1B, fB, b0B);
        __syncthreads();
        if (s + 3 < nk) { loadA_(s + 3, a0B, a1B, fB); loadB_(s + 3, b0B); }
        compute_();
    }

    const float g = gptr ? gptr[0] : 1.0f;

    if (EPI == EPI_CONV) {
#pragma unroll
        for (int fi = 0; fi < 4; fi++) {
            int co = m0 + wm * 64 + fi * 16 + l4 * 4;
            float* Ybase = Yf;
            if (Yf2 != nullptr && co >= Msplit) { co -= Msplit; Ybase = Yf2; }
            float* Yfb = Ybase ? Ybase + (size_t)b * sYb : nullptr;
            unsigned short* Ybfb = Ybf ? Ybf + (size_t)b * sYbfb : nullptr;
            const float* Rfb = Rf ? Rf + (size_t)b * sRb : nullptr;
#pragma unroll
            for (int fj = 0; fj < 2; fj++) {
                const int np = n0 + wn * 32 + fj * 16 + l15;
                const int y = np / 50, x = np - y * 50;
                if (y >= 48 || x >= 48) continue;
                const int nout = y * 48 + x;
#pragma unroll
                for (int rr = 0; rr < 4; rr++) {
                    float o = g * acc[fi][fj][rr];
                    if (bias) o += bias[m0 + wm * 64 + fi * 16 + l4 * 4 + rr];
                    if (Rfb) o += Rfb[(size_t)(co + rr) * HW + nout];
                    if (Yfb) Yfb[(size_t)(co + rr) * HW + nout] = o;
                    if (Ybfb) Ybfb[(size_t)(co + rr) * HW + nout] = f2b(o);
                }
            }
        }
    } else if (EPI == EPI_ROWS) {
        float* Yfb = Yf + (size_t)b * sYb;
#pragma unroll
        for (int fi = 0; fi < 4; fi++) {
            const int mr = m0 + wm * 64 + fi * 16 + l4 * 4;
#pragma unroll
            for (int fj = 0; fj < 2; fj++) {
                const int col = n0 + wn * 32 + fj * 16 + l15;
                if (col >= Nb) continue;
#pragma unroll
                for (int rr = 0; rr < 4; rr++)
                    Yfb[(size_t)(mr + rr) * Nb + col] = acc[fi][fj][rr];
            }
        }
    } else { // EPI_PVXP
        unsigned short* Yb = Ybf + (size_t)b * sYbfb;
        const unsigned short* Rbb = Rb + (size_t)b * sRbb;
#pragma unroll
        for (int fi = 0; fi < 4; fi++) {
            const int ms0 = m0 + wm * 64 + fi * 16 + l4 * 4;
#pragma unroll
            for (int fj = 0; fj < 2; fj++) {
                const int col = n0 + wn * 32 + fj * 16 + l15;
                if (col >= Nb) continue;
#pragma unroll
                for (int rr = 0; rr < 4; rr++) {
                    const int ms = ms0 + rr;
                    const int yy = ms / 48, xx = ms - yy * 48;
                    const size_t idx = (size_t)((yy + 1) * 50 + xx + 1) * Nb + col;
                    Yb[idx] = f2b(g * acc[fi][fj][rr] + b2f(Rbb[idx]));
                }
            }
        }
    }
}

// ===========================================================================
// fp32 [b][C][2304] -> padded channel-last bf16 Xp [b][XPROWS][C]
// (+ optional hi/lo split c-major bf16 [b][C][2304])
// ===========================================================================
template<bool HILO>
__global__ __launch_bounds__(256) void tpad(
    const float* __restrict__ X, unsigned short* __restrict__ Xp,
    unsigned short* __restrict__ hi, unsigned short* __restrict__ lo, int C)
{
    const int t = threadIdx.x;
    const int tj = t & 31, ti = t >> 5;
    const int n0 = blockIdx.x * 32, c0 = blockIdx.y * 32, b = blockIdx.z;
    __shared__ float sm[32][33];
    const float* Xb = X + ((size_t)b * C + c0) * HW + n0;
#pragma unroll
    for (int ii = 0; ii < 4; ii++) {
        const int c = ti + ii * 8;
        const float v = Xb[(size_t)c * HW + tj];
        sm[c][tj] = v;
        if (HILO) {
            const unsigned short h = f2b(v);
            hi[((size_t)b * C + c0 + c) * HW + n0 + tj] = h;
            lo[((size_t)b * C + c0 + c) * HW + n0 + tj] = f2b(v - b2f(h));
        }
    }
    __syncthreads();
    unsigned short* Xpb = Xp + (size_t)b * XPROWS * C;
#pragma unroll
    for (int ii = 0; ii < 4; ii++) {
        const int n = n0 + ti + ii * 8;
        const int y = n / 48, x = n - y * 48;
        Xpb[(size_t)((y + 1) * 50 + x + 1) * C + c0 + tj] = f2b(sm[tj][ti + ii * 8]);
    }
}

// W [Cout][Cin][9] fp32 -> Wp [Cout][tap*Cin+ci] bf16 (tap-major K)
__global__ __launch_bounds__(256) void wconv3(
    const float* __restrict__ Wf, unsigned short* __restrict__ Wb, int Cin)
{
    const int co = blockIdx.x, ci = blockIdx.y * 256 + threadIdx.x;
    const float* src = Wf + ((size_t)co * Cin + ci) * 9;
    unsigned short* dst = Wb + (size_t)co * 9 * Cin + ci;
#pragma unroll
    for (int tap = 0; tap < 9; tap++) dst[(size_t)tap * Cin] = f2b(src[tap]);
}

__global__ __launch_bounds__(256) void cvt_bf16(
    const float* __restrict__ in, unsigned short* __restrict__ o, int n)
{
    const int i = blockIdx.x * 256 + threadIdx.x;
    if (i < n) o[i] = f2b(in[i]);
}

// ===========================================================================
// Training-mode BN (+ReLU), one block per channel
// ===========================================================================
__global__ __launch_bounds__(256) void bn_relu_kernel(
    const float* __restrict__ Xin, float* __restrict__ Yout,
    const float* __restrict__ g, const float* __restrict__ bb, int C)
{
    const int c = blockIdx.x, t = threadIdx.x;
    __shared__ float buf[NCOL];
    __shared__ float redA[256], redB[256];
    float s = 0.f, s2 = 0.f;
    for (int i = t; i < NCOL; i += 256) {
        int b = i / HW, n = i - b * HW;
        float v = Xin[((size_t)b * C + c) * HW + n];
        buf[i] = v; s += v; s2 += v * v;
    }
    redA[t] = s; redB[t] = s2; __syncthreads();
    for (int st = 128; st > 0; st >>= 1) {
        if (t < st) { redA[t] += redA[t + st]; redB[t] += redB[t + st]; }
        __syncthreads();
    }
    float mean = redA[0] * (1.f / NCOL);
    float var  = redB[0] * (1.f / NCOL) - mean * mean;
    float scale = g[c] * rsqrtf(var + 1e-5f);
    float shift = bb[c] - mean * scale;
    for (int i = t; i < NCOL; i += 256) {
        int b = i / HW, n = i - b * HW;
        Yout[((size_t)b * C + c) * HW + n] = fmaxf(buf[i] * scale + shift, 0.f);
    }
}

// fp32 1x1 conv (merged q+k head, M=128)
template<int TAPS>
__global__ __launch_bounds__(256) void conv_gemm(
    const float* __restrict__ X, const float* __restrict__ Wt,
    const float* __restrict__ bias, float* __restrict__ Y,
    int Cin, int Cout)
{
    const int t  = threadIdx.x;
    const int tx = t & 15, ty = t >> 4;
    const int n0 = blockIdx.x * 64;
    const int m0 = blockIdx.y * 64;
    const int K  = Cin * TAPS;
    __shared__ float As[16][68];
    __shared__ float Bs[16][68];
    float acc[4][4] = {};
    const int arow = t >> 2, ac4 = (t & 3) * 4;
    const int bkk  = t >> 4, bnn = (t & 15) * 4;
    int pb[4], pn[4];
#pragma unroll
    for (int i = 0; i < 4; i++) {
        int p = n0 + bnn + i;
        pb[i] = p / HW; pn[i] = p - pb[i] * HW;
    }
    const float* wrow = Wt + (size_t)(m0 + arow) * K + ac4;
    for (int k0 = 0; k0 < K; k0 += 16) {
        float4 a = *(const float4*)(wrow + k0);
        As[ac4+0][arow] = a.x; As[ac4+1][arow] = a.y;
        As[ac4+2][arow] = a.z; As[ac4+3][arow] = a.w;
        int ci = k0 + bkk;
#pragma unroll
        for (int i = 0; i < 4; i++)
            Bs[bkk][bnn + i] = X[((size_t)pb[i] * Cin + ci) * HW + pn[i]];
        __syncthreads();
#pragma unroll
        for (int kk = 0; kk < 16; kk++) {
            float4 a4 = *(const float4*)&As[kk][ty * 4];
            float4 b4 = *(const float4*)&Bs[kk][tx * 4];
            float av[4] = {a4.x, a4.y, a4.z, a4.w};
            float bv[4] = {b4.x, b4.y, b4.z, b4.w};
#pragma unroll
            for (int i = 0; i < 4; i++)
#pragma unroll
                for (int j = 0; j < 4; j++)
                    acc[i][j] = fmaf(av[i], bv[j], acc[i][j]);
        }
        __syncthreads();
    }
#pragma unroll
    for (int i = 0; i < 4; i++) {
        int co = m0 + ty * 4 + i;
        if (co >= Cout) continue;
        float bv = bias ? bias[co] : 0.f;
#pragma unroll
        for (int j = 0; j < 4; j++) {
            int p = n0 + tx * 4 + j;
            int b = p / HW, n = p - b * HW;
            Y[((size_t)b * Cout + co) * HW + n] = acc[i][j] + bv;
        }
    }
}

// PAM energy (fp32, K=64)
__global__ __launch_bounds__(256) void pam_energy_kernel(
    const float* __restrict__ q, const float* __restrict__ k, float* __restrict__ E)
{
    const int t = threadIdx.x, tx = t & 15, ty = t >> 4;
    const int n0 = blockIdx.x * 64, m0 = blockIdx.y * 64;
    __shared__ float qs[64][68], ks[64][68];
    {
        int c4 = (t & 15) * 4, r0 = (t >> 4) * 4;
#pragma unroll
        for (int i = 0; i < 4; i++) {
            *(float4*)&qs[r0 + i][c4] = *(const float4*)&q[(size_t)(r0 + i) * HW + n0 + c4];
            *(float4*)&ks[r0 + i][c4] = *(const float4*)&k[(size_t)(r0 + i) * HW + m0 + c4];
        }
    }
    __syncthreads();
    float acc[4][4] = {};
#pragma unroll 4
    for (int c = 0; c < 64; c++) {
        float4 a4 = *(const float4*)&qs[c][ty * 4];
        float4 b4 = *(const float4*)&ks[c][tx * 4];
        float av[4] = {a4.x, a4.y, a4.z, a4.w};
        float bv[4] = {b4.x, b4.y, b4.z, b4.w};
#pragma unroll
        for (int i = 0; i < 4; i++)
#pragma unroll
            for (int j = 0; j < 4; j++)
                acc[i][j] = fmaf(av[i], bv[j], acc[i][j]);
    }
#pragma unroll
    for (int i = 0; i < 4; i++)
#pragma unroll
        for (int j = 0; j < 4; j++)
            E[(size_t)(n0 + ty * 4 + i) * HW + m0 + tx * 4 + j] = acc[i][j];
}

// Row softmax over 2304, in place
__global__ __launch_bounds__(256) void softmax2304(float* __restrict__ E)
{
    const int t = threadIdx.x;
    float* R = E + (size_t)blockIdx.x * HW;
    __shared__ float buf[HW];
    __shared__ float red[256];
    float m = -1e30f;
    for (int i = t; i < HW; i += 256) { float v = R[i]; buf[i] = v; m = fmaxf(m, v); }
    red[t] = m; __syncthreads();
    for (int st = 128; st > 0; st >>= 1) { if (t < st) red[t] = fmaxf(red[t], red[t + st]); __syncthreads(); }
    m = red[0]; __syncthreads();
    float s = 0.f;
    for (int i = t; i < HW; i += 256) { float e = __expf(buf[i] - m); buf[i] = e; s += e; }
    red[t] = s; __syncthreads();
    for (int st = 128; st > 0; st >>= 1) { if (t < st) red[t] += red[t + st]; __syncthreads(); }
    float inv = 1.f / red[0];
    for (int i = t; i < HW; i += 256) R[i] = buf[i] * inv;
}

// CAM softmax with hi/lo fixup: E = E1 + E2 + E2^T; attn = exp(min-E)/sum (bf16)
__global__ __launch_bounds__(256) void cam_sm(
    const float* __restrict__ E1, const float* __restrict__ E2,
    unsigned short* __restrict__ attn)
{
    const int c = blockIdx.x, b = blockIdx.y, t = threadIdx.x;
    const float* E1b = E1 + (size_t)b * 512 * 512;
    const float* E2b = E2 + (size_t)b * 512 * 512;
    float v0 = E1b[(size_t)c * 512 + t]       + E2b[(size_t)c * 512 + t]       + E2b[(size_t)t * 512 + c];
    float v1 = E1b[(size_t)c * 512 + t + 256] + E2b[(size_t)c * 512 + t + 256] + E2b[(size_t)(t + 256) * 512 + c];
    __shared__ float red[256];
    red[t] = fminf(v0, v1); __syncthreads();
    for (int st = 128; st; st >>= 1) { if (t < st) red[t] = fminf(red[t], red[t + st]); __syncthreads(); }
    float mn = red[0]; __syncthreads();
    float e0 = __expf(mn - v0), e1 = __expf(mn - v1);
    red[t] = e0 + e1; __syncthreads();
    for (int st = 128; st; st >>= 1) { if (t < st) red[t] += red[t + st]; __syncthreads(); }
    float inv = 1.f / red[0];
    unsigned short* ab = attn + (size_t)b * 512 * 512 + (size_t)c * 512;
    ab[t] = f2b(e0 * inv); ab[t + 256] = f2b(e1 * inv);
}

// Final 1x1 convs to 19 channels. 64 cols/block, 4-way ci split, LDS reduce.
__global__ __launch_bounds__(256) void conv1x1_out19(
    const float* __restrict__ X1, const float* __restrict__ X2,
    const float* __restrict__ Wt, const float* __restrict__ bias,
    float* __restrict__ Y)
{
    __shared__ float ws[19 * 512];
    __shared__ float red[4][19 * 64];
    const int t = threadIdx.x;
    for (int i = t; i < 19 * 512; i += 256) ws[i] = Wt[i];
    const int col = t & 63, qr = t >> 6;
    const int b = blockIdx.y, n = blockIdx.x * 64 + col;
    __syncthreads();
    float acc[19] = {};
    const float* p1 = X1 + (size_t)b * 512 * HW + n;
    const float* p2 = X2 ? X2 + (size_t)b * 512 * HW + n : nullptr;
    const int c0 = qr * 128;
    for (int ci = c0; ci < c0 + 128; ci++) {
        float xv = p1[(size_t)ci * HW];
        if (X2) xv += p2[(size_t)ci * HW];
#pragma unroll
        for (int co = 0; co < 19; co++) acc[co] = fmaf(ws[co * 512 + ci], xv, acc[co]);
    }
#pragma unroll
    for (int co = 0; co < 19; co++) red[qr][co * 64 + col] = acc[co];
    __syncthreads();
    if (qr == 0) {
#pragma unroll
        for (int co = 0; co < 19; co++) {
            float v = red[0][co * 64 + col] + red[1][co * 64 + col]
                    + red[2][co * 64 + col] + red[3][co * 64 + col] + bias[co];
            Y[((size_t)b * 19 + co) * HW + n] = v;
        }
    }
}

// ===========================================================================
extern "C" void kernel_launch(void* const* d_in, const int* in_sizes, int n_in,
                              void* d_out, int out_size, void* d_ws, size_t ws_size,
                              hipStream_t stream)
{
    const float* x    = (const float*)d_in[0];
    const float* w5a  = (const float*)d_in[1];
    const float* g5a  = (const float*)d_in[2];
    const float* b5a  = (const float*)d_in[3];
    const float* w5c  = (const float*)d_in[4];
    const float* g5c  = (const float*)d_in[5];
    const float* b5c  = (const float*)d_in[6];
    const float* wq   = (const float*)d_in[7];
    const float* bq   = (const float*)d_in[8];
    const float* wk   = (const float*)d_in[9];
    const float* bk   = (const float*)d_in[10];
    const float* wv   = (const float*)d_in[11];
    const float* bv   = (const float*)d_in[12];
    const float* gpam = (const float*)d_in[13];
    const float* gcam = (const float*)d_in[14];
    const float* w51  = (const float*)d_in[15];
    const float* g51  = (const float*)d_in[16];
    const float* b51  = (const float*)d_in[17];
    const float* w52  = (const float*)d_in[18];
    const float* g52  = (const float*)d_in[19];
    const float* b52  = (const float*)d_in[20];
    const float* w6   = (const float*)d_in[21];
    const float* b6   = (const float*)d_in[22];
    const float* w7   = (const float*)d_in[23];
    const float* b7   = (const float*)d_in[24];
    const float* w8   = (const float*)d_in[25];
    const float* b8   = (const float*)d_in[26];
    float* out = (float*)d_out;

    char* wsb = (char*)d_ws;
    size_t off = 0;
    auto alloc = [&](size_t bytes) { void* p = wsb + off; off += (bytes + 255) & ~(size_t)255; return p; };

    // persistent
    unsigned short* Xp_x  = (unsigned short*)alloc((size_t)2 * XPROWS * 2048 * 2);  // dies after conv5ac -> arena2
    float*          feat1 = (float*)alloc((size_t)2 * 512 * HW * 4);                // -> saconv overlay
    float*          feat2 = (float*)alloc((size_t)2 * 512 * HW * 4);                // -> scconv overlay
    unsigned short* Xp_f1 = (unsigned short*)alloc((size_t)2 * XPROWS * 512 * 2);
    unsigned short* Xp_f2 = (unsigned short*)alloc((size_t)2 * XPROWS * 512 * 2);
    unsigned short* hi_cm = (unsigned short*)alloc((size_t)2 * 512 * HW * 2);
    unsigned short* lo_cm = (unsigned short*)alloc((size_t)2 * 512 * HW * 2);
    float*          qkb   = (float*)alloc((size_t)2 * 128 * HW * 4);
    unsigned short* vbf   = (unsigned short*)alloc((size_t)2 * 512 * HW * 2);
    unsigned short* Wpv   = (unsigned short*)alloc((size_t)512 * 512 * 2);
    float*          wqk   = (float*)alloc((size_t)128 * 512 * 4);
    float*          bqk   = (float*)alloc((size_t)128 * 4);
    // arena1: Wp5a+Wp5c (contiguous -> merged M=1024 A), reused after conv5ac
    char* arena1 = (char*)alloc((size_t)2 * 512 * 18432 * 2);                        // 37.75MB
    unsigned short* Wp5ac = (unsigned short*)arena1;
    float*          energy= (float*)arena1;                                          // 21.23MB
    unsigned short* Xp51  = (unsigned short*)(arena1 + 21233664);                    // 5.24MB
    unsigned short* Wp51  = (unsigned short*)(arena1 + 21233664 + 5242880);          // 4.72MB
    unsigned short* Wp52  = (unsigned short*)(arena1 + 21233664 + 5242880 + 4718592);
    // arena2: overlays Xp_x (20.97MB)
    char* arena2 = (char*)Xp_x;
    float*          scfeat = (float*)arena2;                                          // 9.44MB
    unsigned short* Xp52   = (unsigned short*)(arena2 + 9437184);                     // 5.24MB
    float*          E1     = (float*)(arena2 + 9437184 + 5242880);                    // 2MB
    float*          E2     = (float*)(arena2 + 9437184 + 5242880 + 2097152);          // 2MB
    unsigned short* camattn= (unsigned short*)(arena2 + 9437184 + 5242880 + 2 * 2097152);
    float* saconv = feat1;
    float* scconv = feat2;
    (void)in_sizes; (void)n_in; (void)out_size; (void)ws_size;

    dim3 blk(256);
    const long XF1S = (long)XPROWS * 512;

    // --- prep ---
    hipMemsetAsync(Xp_x,  0, (size_t)2 * XPROWS * 2048 * 2, stream);
    hipMemsetAsync(Xp_f1, 0, (size_t)2 * XPROWS * 512 * 2, stream);
    hipMemsetAsync(Xp_f2, 0, (size_t)2 * XPROWS * 512 * 2, stream);
    wconv3<<<dim3(512, 8), blk, 0, stream>>>(w5a, Wp5ac, 2048);
    wconv3<<<dim3(512, 8), blk, 0, stream>>>(w5c, Wp5ac + (size_t)512 * 18432, 2048);
    cvt_bf16<<<1024, blk, 0, stream>>>(wv, Wpv, 512 * 512);
    hipMemcpyAsync(wqk, wq, (size_t)64 * 512 * 4, hipMemcpyDeviceToDevice, stream);
    hipMemcpyAsync(wqk + 64 * 512, wk, (size_t)64 * 512 * 4, hipMemcpyDeviceToDevice, stream);
    hipMemcpyAsync(bqk, bq, 64 * 4, hipMemcpyDeviceToDevice, stream);
    hipMemcpyAsync(bqk + 64, bk, 64 * 4, hipMemcpyDeviceToDevice, stream);
    tpad<false><<<dim3(72, 64, 2), blk, 0, stream>>>(x, Xp_x, nullptr, nullptr, 2048);

    // --- merged conv5a+conv5c (M=1024) + BN ---
    mm<9, false, EPI_CONV><<<dim3(38, 8, 2), blk, 0, stream>>>(
        Wp5ac, 0, Xp_x, (long)XPROWS * 2048, 18432, 11, 0,
        feat1, (long)512 * HW, 512, feat2, nullptr, 0,
        nullptr, nullptr, nullptr, 0, nullptr, 0);
    bn_relu_kernel<<<512, blk, 0, stream>>>(feat1, feat1, g5a, b5a, 512);
    bn_relu_kernel<<<512, blk, 0, stream>>>(feat2, feat2, g5c, b5c, 512);
    // Xp_x dead -> arena2 usable; Wp5ac dead -> arena1 reuse
    hipMemsetAsync(Xp51, 0, (size_t)2 * XPROWS * 512 * 2, stream);
    hipMemsetAsync(Xp52, 0, (size_t)2 * XPROWS * 512 * 2, stream);

    tpad<false><<<dim3(72, 16, 2), blk, 0, stream>>>(feat1, Xp_f1, nullptr, nullptr, 512);
    tpad<true ><<<dim3(72, 16, 2), blk, 0, stream>>>(feat2, Xp_f2, hi_cm, lo_cm, 512);

    // --- PAM q/k (merged, fp32) and v (MFMA) ---
    mm<1, false, EPI_CONV><<<dim3(38, 4, 2), blk, 0, stream>>>(
        Wpv, 0, Xp_f1, XF1S, 512, 9, 0,
        nullptr, 0, 0, nullptr, vbf, (long)512 * HW,
        bv, nullptr, nullptr, 0, nullptr, 0);
    conv_gemm<1><<<dim3(72, 2), blk, 0, stream>>>(feat1, wqk, bqk, qkb, 512, 128);
    wconv3<<<dim3(512, 2), blk, 0, stream>>>(w51, Wp51, 512);
    wconv3<<<dim3(512, 2), blk, 0, stream>>>(w52, Wp52, 512);

    // --- PAM attention per batch; PV writes padded sa_featT directly ---
    for (int b = 0; b < 2; b++) {
        const float* qb = qkb + (size_t)b * 128 * HW;
        const float* kb = qb + (size_t)64 * HW;
        pam_energy_kernel<<<dim3(36, 36), blk, 0, stream>>>(qb, kb, energy);
        softmax2304<<<HW, blk, 0, stream>>>(energy);
        mm<1, true, EPI_PVXP><<<dim3(8, 18, 1), blk, 0, stream>>>(
            energy, 0, vbf + (size_t)b * 512 * HW, 0, HW, 0, 512,
            nullptr, 0, 0, nullptr, Xp51 + (size_t)b * XF1S, 0,
            nullptr, gpam, nullptr, 0, Xp_f1 + (size_t)b * XF1S, 0);
    }

    // --- conv51 + BN (saconv overlays feat1; feat1 dead after q/k) ---
    mm<9, false, EPI_CONV><<<dim3(38, 4, 2), blk, 0, stream>>>(
        Wp51, 0, Xp51, XF1S, 4608, 9, 0,
        saconv, (long)512 * HW, 0, nullptr, nullptr, 0,
        nullptr, nullptr, nullptr, 0, nullptr, 0);
    bn_relu_kernel<<<512, blk, 0, stream>>>(saconv, saconv, g51, b51, 512);

    // --- CAM: split-bf16 Gram, softmax, out ---
    mm<1, false, EPI_ROWS><<<dim3(8, 4, 2), blk, 0, stream>>>(
        hi_cm, (long)512 * HW, hi_cm, (long)512 * HW, HW, 0, 512,
        E1, (long)512 * 512, 0, nullptr, nullptr, 0,
        nullptr, nullptr, nullptr, 0, nullptr, 0);
    mm<1, false, EPI_ROWS><<<dim3(8, 4, 2), blk, 0, stream>>>(
        hi_cm, (long)512 * HW, lo_cm, (long)512 * HW, HW, 0, 512,
        E2, (long)512 * 512, 0, nullptr, nullptr, 0,
        nullptr, nullptr, nullptr, 0, nullptr, 0);
    cam_sm<<<dim3(512, 2), blk, 0, stream>>>(E1, E2, camattn);
    mm<1, false, EPI_CONV><<<dim3(38, 4, 2), blk, 0, stream>>>(
        camattn, (long)512 * 512, Xp_f2, XF1S, 512, 9, 0,
        scfeat, (long)512 * HW, 0, nullptr, nullptr, 0,
        nullptr, gcam, feat2, (long)512 * HW, nullptr, 0);

    // --- conv52 + BN (scconv overlays feat2, dead after cam residual) ---
    tpad<false><<<dim3(72, 16, 2), blk, 0, stream>>>(scfeat, Xp52, nullptr, nullptr, 512);
    mm<9, false, EPI_CONV><<<dim3(38, 4, 2), blk, 0, stream>>>(
        Wp52, 0, Xp52, XF1S, 4608, 9, 0,
        scconv, (long)512 * HW, 0, nullptr, nullptr, 0,
        nullptr, nullptr, nullptr, 0, nullptr, 0);
    bn_relu_kernel<<<512, blk, 0, stream>>>(scconv, scconv, g52, b52, 512);

    // --- output heads: (sasc, sa, sc) ---
    conv1x1_out19<<<dim3(36, 2), blk, 0, stream>>>(saconv, nullptr, w6, b6, out + 87552);
    conv1x1_out19<<<dim3(36, 2), blk, 0, stream>>>(scconv, nullptr, w7, b7, out + 2 * 87552);
    conv1x1_out19<<<dim3(36, 2), blk, 0, stream>>>(saconv, scconv, w8, b8, out + 0);
}